// Round 9
// baseline (128.541 us; speedup 1.0000x reference)
//
#include <hip/hip_runtime.h>
#include <hip/hip_bf16.h>
#include <type_traits>
#include <utility>

// Fused 2-layer Elman RNN + FC, round 9: wave-specialized layer pipeline.
// B=16384, T=28, IN=28, H1=128, H2=64, NC=10.
// 1024 blocks x 384 thr; block owns 16 batch rows.
//   waves 0-3 ("L1"): layer-1, N-split-4 over H1=128 (32 cols each)
//   waves 4-5 ("L2"): layer-2 + FC, N-split-2 over H2=64 (32 cols each)
// Period p: L1 computes h1(p) (using h1(p-1)); L2 computes h2(p-1) (using
// h1(p-1), h2(p-2)) + FC term tau=p-2. ONE barrier per period, 29 periods
// (R6 had 56 barriers). Critical path per period = max(L1,L2), not sum.
// Prepass bf16 weights in d_ws; native __bf16 casts; XOR-16 LDS swizzle.

#define NBLK 1024
#define NTHR 384

typedef float  f32x4 __attribute__((ext_vector_type(4)));
typedef short  s16x8 __attribute__((ext_vector_type(8)));
typedef __bf16 b16x8 __attribute__((ext_vector_type(8)));

template <typename V, typename = void> struct mfma_ok : std::false_type {};
template <typename V>
struct mfma_ok<V, std::void_t<decltype(__builtin_amdgcn_mfma_f32_16x16x32_bf16(
    std::declval<V>(), std::declval<V>(), std::declval<f32x4>(), 0, 0, 0))>>
    : std::true_type {};
using frag_t = std::conditional_t<mfma_ok<b16x8>::value, b16x8, s16x8>;

__device__ __forceinline__ f32x4 MFMA(frag_t a, frag_t b, f32x4 c) {
  return __builtin_amdgcn_mfma_f32_16x16x32_bf16(a, b, c, 0, 0, 0);
}

__device__ __forceinline__ unsigned short f2bf_n(float f) {  // native cvt (RNE)
  __bf16 h = (__bf16)f;
  return __builtin_bit_cast(unsigned short, h);
}
__device__ __forceinline__ frag_t packx(float4 a, float4 b) {
  s16x8 r;
  r[0]=(short)f2bf_n(a.x); r[1]=(short)f2bf_n(a.y); r[2]=(short)f2bf_n(a.z); r[3]=(short)f2bf_n(a.w);
  r[4]=(short)f2bf_n(b.x); r[5]=(short)f2bf_n(b.y); r[6]=(short)f2bf_n(b.z); r[7]=(short)f2bf_n(b.w);
  return __builtin_bit_cast(frag_t, r);
}
__device__ __forceinline__ float tanh_fast(float v) {
  float e = __expf(2.0f * v);
  return 1.0f - 2.0f / (e + 1.0f);
}

// ---- bf16 weight cache layout in d_ws (u16 elements) ----
#define OFF_WIH1 0        // [128][32]  (K padded 28->32 with zeros)
#define OFF_WHH1 4096     // [128][128]
#define OFF_WIH2 20480    // [64][128]
#define OFF_WHH2 28672    // [64][64]
#define OFF_WFC  32768    // [10][1792]
#define WS_U16   50688

__global__ void cvt_weights(const float* __restrict__ wih1, const float* __restrict__ whh1,
                            const float* __restrict__ wih2, const float* __restrict__ whh2,
                            const float* __restrict__ wfc,  unsigned short* __restrict__ ws)
{
  int i = blockIdx.x * 256 + threadIdx.x;
  if (i < 4096) {                       // W_ih1 padded
    int r = i >> 5, c = i & 31;
    ws[OFF_WIH1 + i] = (c < 28) ? f2bf_n(wih1[r * 28 + c]) : (unsigned short)0;
    return;
  }
  i -= 4096;
  if (i < 16384) { ws[OFF_WHH1 + i] = f2bf_n(whh1[i]); return; }
  i -= 16384;
  if (i < 8192)  { ws[OFF_WIH2 + i] = f2bf_n(wih2[i]); return; }
  i -= 8192;
  if (i < 4096)  { ws[OFF_WHH2 + i] = f2bf_n(whh2[i]); return; }
  i -= 4096;
  if (i < 17920) { ws[OFF_WFC + i] = f2bf_n(wfc[i]); return; }
}

__global__ __launch_bounds__(NTHR, 2)
void rnn_pipe(const float* __restrict__ x,
              const unsigned short* __restrict__ ws,
              const float* __restrict__ b_ih1, const float* __restrict__ b_hh1,
              const float* __restrict__ b_ih2, const float* __restrict__ b_hh2,
              const float* __restrict__ b_fc,
              float* __restrict__ out)
{
  // LDS: 8704 + 4608 + 2048 = 15,360 B
  __shared__ alignas(16) unsigned short h1s[2][16][136];
  __shared__ alignas(16) unsigned short h2s[2][16][72];
  __shared__ alignas(16) float red[2][16][16];

  const int tid  = threadIdx.x;
  const int w    = tid >> 6;          // 0..5
  const int lane = tid & 63;
  const int li   = lane & 15;         // A-row (batch) / D-col
  const int g    = lane >> 4;         // 0..3 k-group / D-row-group
  const int blk  = blockIdx.x;
  const bool isL1 = (w < 4);
  const int  wn2  = w - 4;            // 0..1 for L2 waves
  // XOR-16 column swizzle: (row,col) stored at col ^ (((row>>3)&1)<<4)
  const int swr  = ((li >> 3) & 1) << 4;          // reads:  row = li
  const int swv  = ((g  >> 1) & 1) << 4;          // writes: row = g*4+r

  // ---- weight B-frags, shared array (branch-disjoint contents) ----
  // L1: wW[kt*2+nt]=Whh1 (8), wW[8+nt]=Wih1 (2)
  // L2: wW[kt*2+nt]=Wih2 (8), wW[8+kt*2+nt]=Whh2 (4)
  frag_t wW[12];
  float bv0, bv1;
  const float* xrow = nullptr;
  const unsigned short* wfp = nullptr;

  if (isL1) {
    const int n = w * 32 + li;
    #pragma unroll
    for (int kt = 0; kt < 4; ++kt)
      #pragma unroll
      for (int nt = 0; nt < 2; ++nt)
        wW[kt * 2 + nt] = *(const frag_t*)(ws + OFF_WHH1 + (n + nt * 16) * 128 + kt * 32 + g * 8);
    #pragma unroll
    for (int nt = 0; nt < 2; ++nt)
      wW[8 + nt] = *(const frag_t*)(ws + OFF_WIH1 + (n + nt * 16) * 32 + g * 8);
    bv0 = b_ih1[n] + b_hh1[n];
    bv1 = b_ih1[n + 16] + b_hh1[n + 16];
    xrow = x + (size_t)(blk * 16 + li) * 784 + g * 8;
  } else {
    const int n = wn2 * 32 + li;
    #pragma unroll
    for (int kt = 0; kt < 4; ++kt)
      #pragma unroll
      for (int nt = 0; nt < 2; ++nt)
        wW[kt * 2 + nt] = *(const frag_t*)(ws + OFF_WIH2 + (n + nt * 16) * 128 + kt * 32 + g * 8);
    #pragma unroll
    for (int kt = 0; kt < 2; ++kt)
      #pragma unroll
      for (int nt = 0; nt < 2; ++nt)
        wW[8 + kt * 2 + nt] = *(const frag_t*)(ws + OFF_WHH2 + (n + nt * 16) * 64 + kt * 32 + g * 8);
    bv0 = b_ih2[n] + b_hh2[n];
    bv1 = b_ih2[n + 16] + b_hh2[n + 16];
    const int cls = (li < 10) ? li : 0;
    wfp = ws + OFF_WFC + cls * 1792 + wn2 * 32 + g * 8;
  }

  // loop-invariant LDS offsets
  const int rk0 = (g * 8) ^ swr;
  const int rk1 = (32 + g * 8) ^ swr;
  const int rk2 = (64 + g * 8) ^ swr;
  const int rk3 = (96 + g * 8) ^ swr;
  const int cbase = isL1 ? w * 32 : wn2 * 32;
  const int wc0 = (cbase ^ swv) + li;
  const int wc1 = ((cbase + 16) ^ swv) + li;

  f32x4 fca = {0.f, 0.f, 0.f, 0.f};

  #pragma unroll 1
  for (int p = 0; p <= 28; ++p) {
    const int cb = p & 1, pb = cb ^ 1;
    if (isL1) {
      // ---- layer 1: h1(p) = tanh(x(p) Wih1^T + h1(p-1) Whh1^T + b) ----
      if (p < 28) {
        float4 xa = *(const float4*)(xrow + p * 28);
        float4 xb = float4{0.f, 0.f, 0.f, 0.f};
        if (g < 3) xb = *(const float4*)(xrow + p * 28 + 4);

        f32x4 a0 = f32x4{bv0, bv0, bv0, bv0};
        f32x4 a1 = f32x4{bv1, bv1, bv1, bv1};
        if (p > 0) {
          frag_t f0 = *(const frag_t*)&h1s[pb][li][rk0];
          frag_t f1 = *(const frag_t*)&h1s[pb][li][rk1];
          frag_t f2 = *(const frag_t*)&h1s[pb][li][rk2];
          frag_t f3 = *(const frag_t*)&h1s[pb][li][rk3];
          a0 = MFMA(f0, wW[0], a0); a1 = MFMA(f0, wW[1], a1);
          a0 = MFMA(f1, wW[2], a0); a1 = MFMA(f1, wW[3], a1);
          a0 = MFMA(f2, wW[4], a0); a1 = MFMA(f2, wW[5], a1);
          a0 = MFMA(f3, wW[6], a0); a1 = MFMA(f3, wW[7], a1);
        }
        frag_t xA = packx(xa, xb);
        a0 = MFMA(xA, wW[8], a0);
        a1 = MFMA(xA, wW[9], a1);
        #pragma unroll
        for (int r = 0; r < 4; ++r) h1s[cb][g * 4 + r][wc0] = f2bf_n(tanh_fast(a0[r]));
        #pragma unroll
        for (int r = 0; r < 4; ++r) h1s[cb][g * 4 + r][wc1] = f2bf_n(tanh_fast(a1[r]));
      }
    } else {
      // ---- layer 2: h2(p-1) = tanh(h1(p-1) Wih2^T + h2(p-2) Whh2^T + b)
      //      + FC term tau = p-2 ----
      if (p >= 1) {
        f32x4 c0 = f32x4{bv0, bv0, bv0, bv0};
        f32x4 c1 = f32x4{bv1, bv1, bv1, bv1};
        frag_t f0 = *(const frag_t*)&h1s[pb][li][rk0];
        frag_t f1 = *(const frag_t*)&h1s[pb][li][rk1];
        frag_t f2 = *(const frag_t*)&h1s[pb][li][rk2];
        frag_t f3 = *(const frag_t*)&h1s[pb][li][rk3];
        c0 = MFMA(f0, wW[0], c0); c1 = MFMA(f0, wW[1], c1);
        c0 = MFMA(f1, wW[2], c0); c1 = MFMA(f1, wW[3], c1);
        c0 = MFMA(f2, wW[4], c0); c1 = MFMA(f2, wW[5], c1);
        c0 = MFMA(f3, wW[6], c0); c1 = MFMA(f3, wW[7], c1);
        if (p >= 2) {
          frag_t h2A0 = *(const frag_t*)&h2s[cb][li][rk0];
          frag_t h2A1 = *(const frag_t*)&h2s[cb][li][rk1];
          c0 = MFMA(h2A0, wW[8],  c0); c1 = MFMA(h2A0, wW[9],  c1);
          c0 = MFMA(h2A1, wW[10], c0); c1 = MFMA(h2A1, wW[11], c1);
          frag_t bfc = *(const frag_t*)(wfp + (p - 2) * 64);
          fca = MFMA(wn2 == 0 ? h2A0 : h2A1, bfc, fca);
        }
        #pragma unroll
        for (int r = 0; r < 4; ++r) h2s[pb][g * 4 + r][wc0] = f2bf_n(tanh_fast(c0[r]));
        #pragma unroll
        for (int r = 0; r < 4; ++r) h2s[pb][g * 4 + r][wc1] = f2bf_n(tanh_fast(c1[r]));
      }
    }
    __syncthreads();
  }

  // ---- epilogue: FC tau=27 (h2(27) is in h2s[1]), reduce, store ----
  if (!isL1) {
    frag_t a   = *(const frag_t*)&h2s[1][li][(wn2 * 32 + g * 8) ^ swr];
    frag_t bfc = *(const frag_t*)(wfp + 27 * 64);
    fca = MFMA(a, bfc, fca);
    #pragma unroll
    for (int r = 0; r < 4; ++r)
      red[wn2][g * 4 + r][li] = fca[r];
  }
  __syncthreads();
  if (tid < 160) {
    const int b = tid / 10, c = tid - b * 10;
    out[(size_t)(blk * 16 + b) * 10 + c] = red[0][b][c] + red[1][b][c] + b_fc[c];
  }
}

extern "C" void kernel_launch(void* const* d_in, const int* in_sizes, int n_in,
                              void* d_out, int out_size, void* d_ws, size_t ws_size,
                              hipStream_t stream) {
  const float* x     = (const float*)d_in[0];
  const float* W_ih1 = (const float*)d_in[1];
  const float* W_hh1 = (const float*)d_in[2];
  const float* b_ih1 = (const float*)d_in[3];
  const float* b_hh1 = (const float*)d_in[4];
  const float* W_ih2 = (const float*)d_in[5];
  const float* W_hh2 = (const float*)d_in[6];
  const float* b_ih2 = (const float*)d_in[7];
  const float* b_hh2 = (const float*)d_in[8];
  const float* W_fc  = (const float*)d_in[9];
  const float* b_fc  = (const float*)d_in[10];
  unsigned short* ws = (unsigned short*)d_ws;

  cvt_weights<<<(WS_U16 + 255) / 256, 256, 0, stream>>>(W_ih1, W_hh1, W_ih2, W_hh2, W_fc, ws);
  rnn_pipe<<<NBLK, NTHR, 0, stream>>>(x, ws, b_ih1, b_hh1, b_ih2, b_hh2, b_fc,
                                      (float*)d_out);
}

// Round 10
// 85.162 us; speedup vs baseline: 1.5094x; 1.5094x over previous
//
#include <hip/hip_runtime.h>
#include <hip/hip_bf16.h>
#include <type_traits>
#include <utility>

// Fused 2-layer Elman RNN + FC, round 10: R6 chassis + FORCED weight residency.
// B=16384, T=28, IN=28, H1=128, H2=64, NC=10.
// 1024 blocks x 256 thr; block owns 16 batch rows; waves N-split-4;
// 2 barriers/step; prepass bf16 weights in d_ws; native __bf16 casts.
// KEY CHANGE vs R6: rounds 3-9 all showed VGPR_Count 56-76 -> the 16 weight
// B-frags (64 VGPR) were NOT register-resident; the compiler sank the loads
// into the t-loop and re-streamed them from L2 every step, putting ~200cy
// load latency in every MFMA chain. An empty `asm volatile("" : "+v")`
// identity on each frag at loop top makes reload illegal (asm output is
// opaque) -> frags pinned in VGPRs. ~120 live VGPR <= 128 keeps the
// grid-supplied 4 waves/SIMD occupancy.

#define NBLK 1024
#define NTHR 256

typedef float  f32x4 __attribute__((ext_vector_type(4)));
typedef short  s16x8 __attribute__((ext_vector_type(8)));
typedef __bf16 b16x8 __attribute__((ext_vector_type(8)));

template <typename V, typename = void> struct mfma_ok : std::false_type {};
template <typename V>
struct mfma_ok<V, std::void_t<decltype(__builtin_amdgcn_mfma_f32_16x16x32_bf16(
    std::declval<V>(), std::declval<V>(), std::declval<f32x4>(), 0, 0, 0))>>
    : std::true_type {};
using frag_t = std::conditional_t<mfma_ok<b16x8>::value, b16x8, s16x8>;

__device__ __forceinline__ f32x4 MFMA(frag_t a, frag_t b, f32x4 c) {
  return __builtin_amdgcn_mfma_f32_16x16x32_bf16(a, b, c, 0, 0, 0);
}

// Pin a 128-bit frag in VGPRs: identity asm whose result is opaque, so the
// compiler cannot rematerialize it by re-loading from memory.
__device__ __forceinline__ void keepreg(frag_t &v) {
  f32x4 t = __builtin_bit_cast(f32x4, v);
  asm volatile("" : "+v"(t));
  v = __builtin_bit_cast(frag_t, t);
}

__device__ __forceinline__ unsigned short f2bf_n(float f) {  // native cvt (RNE)
  __bf16 h = (__bf16)f;
  return __builtin_bit_cast(unsigned short, h);
}
__device__ __forceinline__ frag_t packx(float4 a, float4 b) {
  s16x8 r;
  r[0]=(short)f2bf_n(a.x); r[1]=(short)f2bf_n(a.y); r[2]=(short)f2bf_n(a.z); r[3]=(short)f2bf_n(a.w);
  r[4]=(short)f2bf_n(b.x); r[5]=(short)f2bf_n(b.y); r[6]=(short)f2bf_n(b.z); r[7]=(short)f2bf_n(b.w);
  return __builtin_bit_cast(frag_t, r);
}
__device__ __forceinline__ float tanh_fast(float v) {
  float e = __expf(2.0f * v);
  return 1.0f - 2.0f / (e + 1.0f);
}

// ---- bf16 weight cache layout in d_ws (u16 elements) ----
#define OFF_WIH1 0        // [128][32]  (K padded 28->32 with zeros)
#define OFF_WHH1 4096     // [128][128]
#define OFF_WIH2 20480    // [64][128]
#define OFF_WHH2 28672    // [64][64]
#define OFF_WFC  32768    // [10][1792]
#define WS_U16   50688

__global__ void cvt_weights(const float* __restrict__ wih1, const float* __restrict__ whh1,
                            const float* __restrict__ wih2, const float* __restrict__ whh2,
                            const float* __restrict__ wfc,  unsigned short* __restrict__ ws)
{
  int i = blockIdx.x * 256 + threadIdx.x;
  if (i < 4096) {                       // W_ih1 padded
    int r = i >> 5, c = i & 31;
    ws[OFF_WIH1 + i] = (c < 28) ? f2bf_n(wih1[r * 28 + c]) : (unsigned short)0;
    return;
  }
  i -= 4096;
  if (i < 16384) { ws[OFF_WHH1 + i] = f2bf_n(whh1[i]); return; }
  i -= 16384;
  if (i < 8192)  { ws[OFF_WIH2 + i] = f2bf_n(wih2[i]); return; }
  i -= 8192;
  if (i < 4096)  { ws[OFF_WHH2 + i] = f2bf_n(whh2[i]); return; }
  i -= 4096;
  if (i < 17920) { ws[OFF_WFC + i] = f2bf_n(wfc[i]); return; }
}

__global__ __launch_bounds__(NTHR, 2)
void rnn_mfma10(const float* __restrict__ x,
                const unsigned short* __restrict__ ws,
                const float* __restrict__ b_ih1, const float* __restrict__ b_hh1,
                const float* __restrict__ b_ih2, const float* __restrict__ b_hh2,
                const float* __restrict__ b_fc,
                float* __restrict__ out)
{
  // LDS: 8704 + 4608 + 2048 = 15,360 B
  __shared__ alignas(16) unsigned short h1s[2][16][136];
  __shared__ alignas(16) unsigned short h2s[2][16][72];
  __shared__ alignas(16) float red[2][16][16];

  const int tid  = threadIdx.x;
  const int wn   = tid >> 6;          // wave = N-split index 0..3
  const int lane = tid & 63;
  const int li   = lane & 15;         // A-row (batch) / D-col
  const int g    = lane >> 4;         // 0..3 k-group / D-row-group
  const int blk  = blockIdx.x;
  // XOR-16 column swizzle: (row,col) stored at col ^ (((row>>3)&1)<<4)
  const int swr  = ((li >> 3) & 1) << 4;          // reads:  row = li
  const int swv  = ((g  >> 1) & 1) << 4;          // writes: row = g*4+r

  // ---- weight B-frags: raw bf16 16B loads, PINNED resident below ----
  const int n1 = wn * 32 + li;        // (+nt*16)
  const int n2 = wn * 16 + li;
  frag_t wB1[4][2], wBi1[2], wBi2[4], wB2[2];
  #pragma unroll
  for (int kt = 0; kt < 4; ++kt)
    #pragma unroll
    for (int nt = 0; nt < 2; ++nt)
      wB1[kt][nt] = *(const frag_t*)(ws + OFF_WHH1 + (n1 + nt * 16) * 128 + kt * 32 + g * 8);
  #pragma unroll
  for (int nt = 0; nt < 2; ++nt)
    wBi1[nt] = *(const frag_t*)(ws + OFF_WIH1 + (n1 + nt * 16) * 32 + g * 8);
  #pragma unroll
  for (int kt = 0; kt < 4; ++kt)
    wBi2[kt] = *(const frag_t*)(ws + OFF_WIH2 + n2 * 128 + kt * 32 + g * 8);
  #pragma unroll
  for (int kt = 0; kt < 2; ++kt)
    wB2[kt] = *(const frag_t*)(ws + OFF_WHH2 + n2 * 64 + kt * 32 + g * 8);

  float b1v[2];
  b1v[0] = b_ih1[n1] + b_hh1[n1];
  b1v[1] = b_ih1[n1 + 16] + b_hh1[n1 + 16];
  const float b2v = b_ih2[n2] + b_hh2[n2];

  const float* xrow = x + (size_t)(blk * 16 + li) * 784 + g * 8;
  const int    cls  = (li < 10) ? li : 0;
  const unsigned short* wfp = ws + OFF_WFC + cls * 1792 + (wn & 1) * 32 + g * 8;

  f32x4 fca = {0.f, 0.f, 0.f, 0.f};

  #pragma unroll 1
  for (int t = 0; t < 28; ++t) {
    const int cb = t & 1, pb = cb ^ 1;

    // pin weight frags in VGPRs (empty asm identity -> reload illegal)
    #pragma unroll
    for (int kt = 0; kt < 4; ++kt) { keepreg(wB1[kt][0]); keepreg(wB1[kt][1]); }
    keepreg(wBi1[0]); keepreg(wBi1[1]);
    #pragma unroll
    for (int kt = 0; kt < 4; ++kt) keepreg(wBi2[kt]);
    keepreg(wB2[0]); keepreg(wB2[1]);

    // ---- layer 1 ----
    float4 xa = *(const float4*)(xrow + t * 28);
    float4 xb = float4{0.f, 0.f, 0.f, 0.f};
    if (g < 3) xb = *(const float4*)(xrow + t * 28 + 4);

    f32x4 acc1[2];
    acc1[0] = f32x4{b1v[0], b1v[0], b1v[0], b1v[0]};
    acc1[1] = f32x4{b1v[1], b1v[1], b1v[1], b1v[1]};

    if (t > 0) {
      #pragma unroll
      for (int kt = 0; kt < 4; ++kt) {
        frag_t a = *(const frag_t*)&h1s[pb][li][(kt * 32 + g * 8) ^ swr];
        acc1[0] = MFMA(a, wB1[kt][0], acc1[0]);
        acc1[1] = MFMA(a, wB1[kt][1], acc1[1]);
      }
    }
    {
      frag_t xA = packx(xa, xb);
      acc1[0] = MFMA(xA, wBi1[0], acc1[0]);
      acc1[1] = MFMA(xA, wBi1[1], acc1[1]);
    }

    #pragma unroll
    for (int nt = 0; nt < 2; ++nt) {
      const int colsw = ((wn * 32 + nt * 16) ^ swv) + li;
      #pragma unroll
      for (int r = 0; r < 4; ++r)
        h1s[cb][g * 4 + r][colsw] = f2bf_n(tanh_fast(acc1[nt][r]));
    }

    __syncthreads();   // B1: h1(t) visible

    // ---- layer 2 ----
    f32x4 acc2 = f32x4{b2v, b2v, b2v, b2v};
    #pragma unroll
    for (int kt = 0; kt < 4; ++kt) {
      frag_t a = *(const frag_t*)&h1s[cb][li][(kt * 32 + g * 8) ^ swr];
      acc2 = MFMA(a, wBi2[kt], acc2);
    }
    if (t > 0) {
      #pragma unroll
      for (int kt = 0; kt < 2; ++kt) {
        frag_t a = *(const frag_t*)&h2s[pb][li][(kt * 32 + g * 8) ^ swr];
        acc2 = MFMA(a, wB2[kt], acc2);
      }
    }
    {
      const int colsw = ((wn * 16) ^ swv) + li;
      #pragma unroll
      for (int r = 0; r < 4; ++r)
        h2s[cb][g * 4 + r][colsw] = f2bf_n(tanh_fast(acc2[r]));
    }

    __syncthreads();   // B2: h2(t) visible

    // ---- FC accumulation (waves 0,1 split K=64) ----
    if (wn < 2) {
      frag_t a   = *(const frag_t*)&h2s[cb][li][(wn * 32 + g * 8) ^ swr];
      frag_t bfc = *(const frag_t*)(wfp + t * 64);
      fca = MFMA(a, bfc, fca);
    }
  }

  // ---- epilogue: 2-way K-reduce + bias + store ----
  if (wn < 2) {
    #pragma unroll
    for (int r = 0; r < 4; ++r)
      red[wn][g * 4 + r][li] = fca[r];
  }
  __syncthreads();
  if (tid < 160) {
    const int b = tid / 10, c = tid - b * 10;
    out[(size_t)(blk * 16 + b) * 10 + c] = red[0][b][c] + red[1][b][c] + b_fc[c];
  }
}

extern "C" void kernel_launch(void* const* d_in, const int* in_sizes, int n_in,
                              void* d_out, int out_size, void* d_ws, size_t ws_size,
                              hipStream_t stream) {
  const float* x     = (const float*)d_in[0];
  const float* W_ih1 = (const float*)d_in[1];
  const float* W_hh1 = (const float*)d_in[2];
  const float* b_ih1 = (const float*)d_in[3];
  const float* b_hh1 = (const float*)d_in[4];
  const float* W_ih2 = (const float*)d_in[5];
  const float* W_hh2 = (const float*)d_in[6];
  const float* b_ih2 = (const float*)d_in[7];
  const float* b_hh2 = (const float*)d_in[8];
  const float* W_fc  = (const float*)d_in[9];
  const float* b_fc  = (const float*)d_in[10];
  unsigned short* ws = (unsigned short*)d_ws;

  cvt_weights<<<(WS_U16 + 255) / 256, 256, 0, stream>>>(W_ih1, W_hh1, W_ih2, W_hh2, W_fc, ws);
  rnn_mfma10<<<NBLK, NTHR, 0, stream>>>(x, ws, b_ih1, b_hh1, b_ih2, b_hh2, b_fc,
                                        (float*)d_out);
}

// Round 11
// 62.478 us; speedup vs baseline: 2.0574x; 1.3631x over previous
//
#include <hip/hip_runtime.h>
#include <hip/hip_bf16.h>
#include <type_traits>
#include <utility>

// Fused 2-layer Elman RNN + FC, round 11: R6 chassis + VALU diet v2.
// B=16384, T=28, IN=28, H1=128, H2=64, NC=10.
// 1024 blocks x 256 thr; block owns 16 batch rows; waves N-split-4;
// 2 barriers/step; prepass bf16 weights in d_ws; native __bf16 casts.
// NEW vs R6 (counter-driven: VALUBusy 60% w/ ~400 VALU/wave-step vs ~130
// algorithmic):
//  - tanh via v_rcp_f32 (__builtin_amdgcn_rcpf): kills the ~10-instr
//    IEEE-div sequence (+vcc interlock) per tanh (12/thread/step)
//  - t-loop unrolled by 2 -> cb/pb compile-time, swizzled LDS offsets
//    hoisted -> per-access address VALU folds to immediates

#define NBLK 1024
#define NTHR 256

typedef float  f32x4 __attribute__((ext_vector_type(4)));
typedef short  s16x8 __attribute__((ext_vector_type(8)));
typedef __bf16 b16x8 __attribute__((ext_vector_type(8)));

template <typename V, typename = void> struct mfma_ok : std::false_type {};
template <typename V>
struct mfma_ok<V, std::void_t<decltype(__builtin_amdgcn_mfma_f32_16x16x32_bf16(
    std::declval<V>(), std::declval<V>(), std::declval<f32x4>(), 0, 0, 0))>>
    : std::true_type {};
using frag_t = std::conditional_t<mfma_ok<b16x8>::value, b16x8, s16x8>;

__device__ __forceinline__ f32x4 MFMA(frag_t a, frag_t b, f32x4 c) {
  return __builtin_amdgcn_mfma_f32_16x16x32_bf16(a, b, c, 0, 0, 0);
}

__device__ __forceinline__ unsigned short f2bf_n(float f) {  // native cvt (RNE)
  __bf16 h = (__bf16)f;
  return __builtin_bit_cast(unsigned short, h);
}
__device__ __forceinline__ frag_t packx(float4 a, float4 b) {
  s16x8 r;
  r[0]=(short)f2bf_n(a.x); r[1]=(short)f2bf_n(a.y); r[2]=(short)f2bf_n(a.z); r[3]=(short)f2bf_n(a.w);
  r[4]=(short)f2bf_n(b.x); r[5]=(short)f2bf_n(b.y); r[6]=(short)f2bf_n(b.z); r[7]=(short)f2bf_n(b.w);
  return __builtin_bit_cast(frag_t, r);
}
// tanh(v) = 1 - 2/(exp(2v)+1), with fast v_rcp_f32 instead of IEEE divide.
// rcp is ~1ulp; saturates correctly: e=inf -> rcp=0 -> 1; e=0 -> 1-2 = -1.
__device__ __forceinline__ float tanh_fast(float v) {
  float e = __expf(2.0f * v);
  return fmaf(-2.0f, __builtin_amdgcn_rcpf(e + 1.0f), 1.0f);
}

// ---- bf16 weight cache layout in d_ws (u16 elements) ----
#define OFF_WIH1 0        // [128][32]  (K padded 28->32 with zeros)
#define OFF_WHH1 4096     // [128][128]
#define OFF_WIH2 20480    // [64][128]
#define OFF_WHH2 28672    // [64][64]
#define OFF_WFC  32768    // [10][1792]
#define WS_U16   50688

__global__ void cvt_weights(const float* __restrict__ wih1, const float* __restrict__ whh1,
                            const float* __restrict__ wih2, const float* __restrict__ whh2,
                            const float* __restrict__ wfc,  unsigned short* __restrict__ ws)
{
  int i = blockIdx.x * 256 + threadIdx.x;
  if (i < 4096) {                       // W_ih1 padded
    int r = i >> 5, c = i & 31;
    ws[OFF_WIH1 + i] = (c < 28) ? f2bf_n(wih1[r * 28 + c]) : (unsigned short)0;
    return;
  }
  i -= 4096;
  if (i < 16384) { ws[OFF_WHH1 + i] = f2bf_n(whh1[i]); return; }
  i -= 16384;
  if (i < 8192)  { ws[OFF_WIH2 + i] = f2bf_n(wih2[i]); return; }
  i -= 8192;
  if (i < 4096)  { ws[OFF_WHH2 + i] = f2bf_n(whh2[i]); return; }
  i -= 4096;
  if (i < 17920) { ws[OFF_WFC + i] = f2bf_n(wfc[i]); return; }
}

__global__ __launch_bounds__(NTHR, 2)
void rnn_mfma11(const float* __restrict__ x,
                const unsigned short* __restrict__ ws,
                const float* __restrict__ b_ih1, const float* __restrict__ b_hh1,
                const float* __restrict__ b_ih2, const float* __restrict__ b_hh2,
                const float* __restrict__ b_fc,
                float* __restrict__ out)
{
  // LDS: 8704 + 4608 + 2048 = 15,360 B
  __shared__ alignas(16) unsigned short h1s[2][16][136];
  __shared__ alignas(16) unsigned short h2s[2][16][72];
  __shared__ alignas(16) float red[2][16][16];

  const int tid  = threadIdx.x;
  const int wn   = tid >> 6;          // wave = N-split index 0..3
  const int lane = tid & 63;
  const int li   = lane & 15;         // A-row (batch) / D-col
  const int g    = lane >> 4;         // 0..3 k-group / D-row-group
  const int blk  = blockIdx.x;
  // XOR-16 column swizzle: (row,col) stored at col ^ (((row>>3)&1)<<4)
  const int swr  = ((li >> 3) & 1) << 4;          // reads:  row = li
  const int swv  = ((g  >> 1) & 1) << 4;          // writes: row = g*4+r

  // ---- weight B-frags ----
  const int n1 = wn * 32 + li;        // (+nt*16)
  const int n2 = wn * 16 + li;
  frag_t wB1[4][2], wBi1[2], wBi2[4], wB2[2];
  #pragma unroll
  for (int kt = 0; kt < 4; ++kt)
    #pragma unroll
    for (int nt = 0; nt < 2; ++nt)
      wB1[kt][nt] = *(const frag_t*)(ws + OFF_WHH1 + (n1 + nt * 16) * 128 + kt * 32 + g * 8);
  #pragma unroll
  for (int nt = 0; nt < 2; ++nt)
    wBi1[nt] = *(const frag_t*)(ws + OFF_WIH1 + (n1 + nt * 16) * 32 + g * 8);
  #pragma unroll
  for (int kt = 0; kt < 4; ++kt)
    wBi2[kt] = *(const frag_t*)(ws + OFF_WIH2 + n2 * 128 + kt * 32 + g * 8);
  #pragma unroll
  for (int kt = 0; kt < 2; ++kt)
    wB2[kt] = *(const frag_t*)(ws + OFF_WHH2 + n2 * 64 + kt * 32 + g * 8);

  float b1v[2];
  b1v[0] = b_ih1[n1] + b_hh1[n1];
  b1v[1] = b_ih1[n1 + 16] + b_hh1[n1 + 16];
  const float b2v = b_ih2[n2] + b_hh2[n2];

  const float* xrow = x + (size_t)(blk * 16 + li) * 784 + g * 8;
  const int    cls  = (li < 10) ? li : 0;
  const unsigned short* wfp = ws + OFF_WFC + cls * 1792 + (wn & 1) * 32 + g * 8;

  // loop-invariant LDS offsets (compile-time cb via unroll-2 below)
  const int rk[4] = { (g * 8) ^ swr, (32 + g * 8) ^ swr,
                      (64 + g * 8) ^ swr, (96 + g * 8) ^ swr };
  const int rfc  = (wn * 32 + g * 8) ^ swr;       // FC read (waves 0,1)
  const int wcA0 = ((wn * 32) ^ swv) + li;        // L1 store cols
  const int wcA1 = ((wn * 32 + 16) ^ swv) + li;
  const int wcB  = ((wn * 16) ^ swv) + li;        // L2 store col

  f32x4 fca = {0.f, 0.f, 0.f, 0.f};

#define RNN_STEP(CB, PB, T)                                                   \
  {                                                                           \
    const int t_ = (T);                                                       \
    /* ---- layer 1 ---- */                                                   \
    float4 xa = *(const float4*)(xrow + t_ * 28);                             \
    float4 xb = float4{0.f, 0.f, 0.f, 0.f};                                   \
    if (g < 3) xb = *(const float4*)(xrow + t_ * 28 + 4);                     \
    f32x4 acc1[2];                                                            \
    acc1[0] = f32x4{b1v[0], b1v[0], b1v[0], b1v[0]};                          \
    acc1[1] = f32x4{b1v[1], b1v[1], b1v[1], b1v[1]};                          \
    if (t_ > 0) {                                                             \
      _Pragma("unroll")                                                       \
      for (int kt = 0; kt < 4; ++kt) {                                        \
        frag_t a = *(const frag_t*)&h1s[PB][li][rk[kt]];                      \
        acc1[0] = MFMA(a, wB1[kt][0], acc1[0]);                               \
        acc1[1] = MFMA(a, wB1[kt][1], acc1[1]);                               \
      }                                                                       \
    }                                                                         \
    {                                                                         \
      frag_t xA = packx(xa, xb);                                              \
      acc1[0] = MFMA(xA, wBi1[0], acc1[0]);                                   \
      acc1[1] = MFMA(xA, wBi1[1], acc1[1]);                                   \
    }                                                                         \
    _Pragma("unroll")                                                         \
    for (int r = 0; r < 4; ++r)                                               \
      h1s[CB][g * 4 + r][wcA0] = f2bf_n(tanh_fast(acc1[0][r]));               \
    _Pragma("unroll")                                                         \
    for (int r = 0; r < 4; ++r)                                               \
      h1s[CB][g * 4 + r][wcA1] = f2bf_n(tanh_fast(acc1[1][r]));               \
    __syncthreads();   /* B1: h1(t) visible */                                \
    /* ---- layer 2 ---- */                                                   \
    f32x4 acc2 = f32x4{b2v, b2v, b2v, b2v};                                   \
    _Pragma("unroll")                                                         \
    for (int kt = 0; kt < 4; ++kt) {                                          \
      frag_t a = *(const frag_t*)&h1s[CB][li][rk[kt]];                        \
      acc2 = MFMA(a, wBi2[kt], acc2);                                         \
    }                                                                         \
    if (t_ > 0) {                                                             \
      _Pragma("unroll")                                                       \
      for (int kt = 0; kt < 2; ++kt) {                                        \
        frag_t a = *(const frag_t*)&h2s[PB][li][rk[kt]];                      \
        acc2 = MFMA(a, wB2[kt], acc2);                                        \
      }                                                                       \
    }                                                                         \
    _Pragma("unroll")                                                         \
    for (int r = 0; r < 4; ++r)                                               \
      h2s[CB][g * 4 + r][wcB] = f2bf_n(tanh_fast(acc2[r]));                   \
    __syncthreads();   /* B2: h2(t) visible */                                \
    /* ---- FC accumulation (waves 0,1 split K=64) ---- */                    \
    if (wn < 2) {                                                             \
      frag_t a   = *(const frag_t*)&h2s[CB][li][rfc];                         \
      frag_t bfc = *(const frag_t*)(wfp + t_ * 64);                           \
      fca = MFMA(a, bfc, fca);                                                \
    }                                                                         \
  }

  #pragma unroll 1
  for (int t2 = 0; t2 < 28; t2 += 2) {
    RNN_STEP(0, 1, t2)
    RNN_STEP(1, 0, t2 + 1)
  }
#undef RNN_STEP

  // ---- epilogue: 2-way K-reduce + bias + store ----
  if (wn < 2) {
    #pragma unroll
    for (int r = 0; r < 4; ++r)
      red[wn][g * 4 + r][li] = fca[r];
  }
  __syncthreads();
  if (tid < 160) {
    const int b = tid / 10, c = tid - b * 10;
    out[(size_t)(blk * 16 + b) * 10 + c] = red[0][b][c] + red[1][b][c] + b_fc[c];
  }
}

extern "C" void kernel_launch(void* const* d_in, const int* in_sizes, int n_in,
                              void* d_out, int out_size, void* d_ws, size_t ws_size,
                              hipStream_t stream) {
  const float* x     = (const float*)d_in[0];
  const float* W_ih1 = (const float*)d_in[1];
  const float* W_hh1 = (const float*)d_in[2];
  const float* b_ih1 = (const float*)d_in[3];
  const float* b_hh1 = (const float*)d_in[4];
  const float* W_ih2 = (const float*)d_in[5];
  const float* W_hh2 = (const float*)d_in[6];
  const float* b_ih2 = (const float*)d_in[7];
  const float* b_hh2 = (const float*)d_in[8];
  const float* W_fc  = (const float*)d_in[9];
  const float* b_fc  = (const float*)d_in[10];
  unsigned short* ws = (unsigned short*)d_ws;

  cvt_weights<<<(WS_U16 + 255) / 256, 256, 0, stream>>>(W_ih1, W_hh1, W_ih2, W_hh2, W_fc, ws);
  rnn_mfma11<<<NBLK, NTHR, 0, stream>>>(x, ws, b_ih1, b_hh1, b_ih2, b_hh2, b_fc,
                                        (float*)d_out);
}